// Round 2
// baseline (194.719 us; speedup 1.0000x reference)
//
#include <hip/hip_runtime.h>

// SpatialGrid2D: bilinear interpolation of an HxWxC=1024x1024x8 f32 table at
// N=4194304 uv points.
//
// Layout facts:
//  - uvList: N x 2 f32 (u=x, v=y), contiguous -> load as float2.
//  - table: [H][W][C] f32, C=8 -> each texel is 32 B; two adjacent texels
//    (ix, ix+1) in one row are 64 B contiguous -> 2x float4 x 2 loads per row.
//  - out: N x 8 f32 -> 2x float4 per thread, consecutive threads contiguous.
//
// One thread per point. Non-temporal stores for the output (written once,
// never re-read) so the 32 MB table stays resident in L2/L3.
//
// Note: __builtin_nontemporal_* requires clang native vector types, not
// HIP_vector_type classes -> use ext_vector_type typedefs.

typedef float float2_t __attribute__((ext_vector_type(2)));
typedef float float4_t __attribute__((ext_vector_type(4)));

__global__ __launch_bounds__(256) void spatial_grid2d_kernel(
    const float2_t* __restrict__ uv,
    const float4_t* __restrict__ table4,   // table viewed as float4: [H][W][2]
    float4_t* __restrict__ out4,           // out viewed as float4: [N][2]
    int n)
{
    int i = blockIdx.x * blockDim.x + threadIdx.x;
    if (i >= n) return;

    float2_t p = __builtin_nontemporal_load(&uv[i]);

    const float sx = 1023.0f;  // W - 1
    const float sy = 1023.0f;  // H - 1
    float xf = p.x * sx;
    float yf = p.y * sy;
    int ix = (int)xf;          // trunc toward zero; uv >= 0 so matches ref
    int iy = (int)yf;
    float alpha = xf - (float)ix;
    float beta  = yf - (float)iy;

    // Row base in float4 units: row stride = W * (C/4) = 1024 * 2 = 2048.
    const float4_t* r0 = table4 + ((size_t)iy * 2048 + (size_t)ix * 2);
    const float4_t* r1 = r0 + 2048;

    // a = table[iy, ix], b = table[iy, ix+1] -> 4x float4 from row iy
    float4_t a0 = r0[0], a1 = r0[1];
    float4_t b0 = r0[2], b1 = r0[3];
    // c = table[iy+1, ix], d = table[iy+1, ix+1]
    float4_t c0 = r1[0], c1 = r1[1];
    float4_t d0 = r1[2], d1 = r1[3];

    float ia = 1.0f - alpha;
    float ib = 1.0f - beta;

    // p = a*(1-alpha) + alpha*b ; q = c*(1-alpha) + alpha*d
    // out = p*(1-beta) + beta*q   (element-wise over 8 channels)
    float4_t p0 = a0 * ia + alpha * b0;
    float4_t q0 = c0 * ia + alpha * d0;
    float4_t o0 = p0 * ib + beta * q0;

    float4_t p1 = a1 * ia + alpha * b1;
    float4_t q1 = c1 * ia + alpha * d1;
    float4_t o1 = p1 * ib + beta * q1;

    // Output written once, never re-read: non-temporal to keep table in cache.
    __builtin_nontemporal_store(o0, &out4[(size_t)i * 2 + 0]);
    __builtin_nontemporal_store(o1, &out4[(size_t)i * 2 + 1]);
}

extern "C" void kernel_launch(void* const* d_in, const int* in_sizes, int n_in,
                              void* d_out, int out_size, void* d_ws, size_t ws_size,
                              hipStream_t stream)
{
    const float2_t* uv     = (const float2_t*)d_in[0];
    const float4_t* table4 = (const float4_t*)d_in[1];
    float4_t* out4         = (float4_t*)d_out;

    int n = in_sizes[0] / 2;  // N points (uvList is N x 2)

    int block = 256;
    int grid = (n + block - 1) / block;
    spatial_grid2d_kernel<<<grid, block, 0, stream>>>(uv, table4, out4, n);
}

// Round 3
// 194.709 us; speedup vs baseline: 1.0001x; 1.0001x over previous
//
#include <hip/hip_runtime.h>

// SpatialGrid2D: bilinear interpolation of an HxWxC=1024x1024x8 f32 table at
// N=4194304 uv points.
//
// Round-3 structure: TWO lanes per point (lane h = point's float4-half h).
// Rationale (rocprof round 2): 195 us with VALUBusy=2.6%, FETCH=592 MB,
// hbm BW only 48% -> neither HBM- nor VALU-bound. Bottleneck = TA/L1
// address processing: thread-per-point issues 8 fully-divergent dwordx4
// loads (64 distinct lines per instruction). With 2 lanes/point, adjacent
// lane pairs access contiguous 32 B -> ~half the distinct lines per
// instruction and half the load instructions; stores become fully
// coalesced (all 64 lanes, 1 KB/wave contiguous).
//
// Per lane (h = t&1, p = t>>1):
//   a_h = table[iy  , ix  ][4h..4h+3]   (f4 index off + h)
//   b_h = table[iy  , ix+1][...]        (off + 2 + h)
//   c_h = table[iy+1, ix  ][...]        (off + 2048 + h)
//   d_h = table[iy+1, ix+1][...]        (off + 2048 + 2 + h)
//   out4[2p+h] = lerp_y(lerp_x(a,b), lerp_x(c,d))   -- all in-lane, no shfl.

typedef float float2_t __attribute__((ext_vector_type(2)));
typedef float float4_t __attribute__((ext_vector_type(4)));

__global__ __launch_bounds__(256) void spatial_grid2d_kernel(
    const float2_t* __restrict__ uv,
    const float4_t* __restrict__ table4,   // table as float4: [H][W][2]
    float4_t* __restrict__ out4,           // out as float4: [N][2]
    int n2)                                // 2 * N
{
    int t = blockIdx.x * blockDim.x + threadIdx.x;
    if (t >= n2) return;

    int p = t >> 1;       // point index
    int h = t & 1;        // which float4 half of the 8-channel texel

    // Both lanes of a pair load the same 8 B -> merged in TA/L1.
    float2_t uvp = uv[p];

    const float sx = 1023.0f;  // W - 1
    const float sy = 1023.0f;  // H - 1
    float xf = uvp.x * sx;
    float yf = uvp.y * sy;
    int ix = (int)xf;          // trunc; uv in [0,1) so ix <= 1022
    int iy = (int)yf;
    float alpha = xf - (float)ix;
    float beta  = yf - (float)iy;

    // Row stride in float4 units: W * (C/4) = 2048.
    size_t off = (size_t)iy * 2048 + (size_t)ix * 2 + (size_t)h;

    float4_t a = table4[off];
    float4_t b = table4[off + 2];
    float4_t c = table4[off + 2048];
    float4_t d = table4[off + 2050];

    float ia = 1.0f - alpha;
    float ib = 1.0f - beta;

    float4_t px = a * ia + alpha * b;
    float4_t qx = c * ia + alpha * d;
    float4_t o  = px * ib + beta * qx;

    // t enumerates out4 directly: out4[2p + h] = out4[t]. Fully coalesced.
    __builtin_nontemporal_store(o, &out4[(size_t)t]);
}

extern "C" void kernel_launch(void* const* d_in, const int* in_sizes, int n_in,
                              void* d_out, int out_size, void* d_ws, size_t ws_size,
                              hipStream_t stream)
{
    const float2_t* uv     = (const float2_t*)d_in[0];
    const float4_t* table4 = (const float4_t*)d_in[1];
    float4_t* out4         = (float4_t*)d_out;

    int n  = in_sizes[0] / 2;  // N points
    int n2 = n * 2;            // 2 threads per point

    int block = 256;
    int grid = (n2 + block - 1) / block;
    spatial_grid2d_kernel<<<grid, block, 0, stream>>>(uv, table4, out4, n2);
}